// Round 7
// baseline (310.344 us; speedup 1.0000x reference)
//
#include <hip/hip_runtime.h>

#define LOG2E 1.4426950408889634f

typedef __attribute__((ext_vector_type(8))) short frag_ab;   // 8 bf16 (4 VGPRs)
typedef __attribute__((ext_vector_type(4))) float frag_cd;   // 4 fp32 acc

// fp32 -> bf16 bits, round-to-nearest-even (inputs finite)
__device__ inline short f2bf(float f) {
    union { float f; unsigned u; } v; v.f = f;
    unsigned r = v.u + 0x7fffu + ((v.u >> 16) & 1u);
    return (short)(r >> 16);
}

// x += row_ror<N>(x) on the VALU pipe (DPP), within each 16-lane row.
template<int CTRL>
__device__ inline float dpp_ror_add(float x) {
    int t = __builtin_amdgcn_update_dpp(0, __builtin_bit_cast(int, x), CTRL, 0xf, 0xf, false);
    return x + __builtin_bit_cast(float, t);
}

// pack 4+4 floats into one bf16 fragment
#define PACK_AF(af, p0, p1)                                                   \
    af[0] = f2bf(p0.x); af[1] = f2bf(p0.y); af[2] = f2bf(p0.z); af[3] = f2bf(p0.w); \
    af[4] = f2bf(p1.x); af[5] = f2bf(p1.y); af[6] = f2bf(p1.z); af[7] = f2bf(p1.w);

// Convert W[128][1024] fp32 -> wbf bf16 in MFMA *fragment order*:
//   element (h,k): chunk c=k>>6, kstep s=(k>>5)&1, kg=(k>>3)&3, j=k&7,
//   ntile nt=h>>4, m=h&15, lane=kg*16+m
//   wbf[ (((c*8+nt)*2+s)*64 + lane)*8 + j ]
__global__ __launch_bounds__(256) void prep_kernel(const float* __restrict__ W,
                                                   short* __restrict__ wbf) {
    int g = blockIdx.x * 256 + threadIdx.x;   // 0..16383
    int h = g >> 7;
    int k0 = (g & 127) << 3;
    const float* src = W + h * 1024 + k0;
    float4 w0 = *(const float4*)src;
    float4 w1 = *(const float4*)(src + 4);
    frag_ab af;
    PACK_AF(af, w0, w1);
    int c = k0 >> 6, s = (k0 >> 5) & 1, kg = (k0 >> 3) & 3;
    int nt = h >> 4, m = h & 15, lane = kg * 16 + m;
    int dst = (((c * 8 + nt) * 2 + s) * 64 + lane) * 8;
    *(frag_ab*)(wbf + dst) = af;
}

// proj: vm[row][h] = sum_k x[row][k]*W[h][k].
// BARRIER-FREE: no LDS. Each wave independently owns 16 rows x all 128 h.
// B fragments are read per-wave straight from wbf (L2-resident 256 KB; the
// current 16 KB chunk is L1-resident since all 4 waves of a block walk the
// same addresses). A (x, HBM) prefetched 1 chunk ahead in registers. With no
// __syncthreads there is no vmcnt(0) drain -- the compiler pipelines loads
// across chunks with counted waits, and waves run mutually unsynchronized.
__global__ __launch_bounds__(256, 4) void proj_kernel(const float* __restrict__ x,
                                                      const short* __restrict__ wbf,
                                                      float* __restrict__ vm) {
    const int tid = threadIdx.x;
    const int lane = tid & 63, wave = tid >> 6;
    const int m = lane & 15, kg = lane >> 4;
    const long rowbase = (long)blockIdx.x * 64 + wave * 16;
    const float* xrow = x + (rowbase + m) * 1024 + kg * 8;
    // frag pointer for this lane; chunk c starts at frag index c*1024 + lane
    const frag_ab* wb = (const frag_ab*)wbf + lane;

    frag_cd acc[8];
#pragma unroll
    for (int nt = 0; nt < 8; ++nt) acc[nt] = (frag_cd){0.f, 0.f, 0.f, 0.f};

    // prefetch A chunk 0
    float4 a0 = *(const float4*)(xrow);
    float4 a1 = *(const float4*)(xrow + 4);
    float4 a2 = *(const float4*)(xrow + 32);
    float4 a3 = *(const float4*)(xrow + 36);

    for (int c = 0; c < 16; ++c) {
        float4 n0, n1, n2, n3;
        if (c < 15) {
            const float* xn = xrow + (c + 1) * 64;
            n0 = *(const float4*)(xn);
            n1 = *(const float4*)(xn + 4);
            n2 = *(const float4*)(xn + 32);
            n3 = *(const float4*)(xn + 36);
        }
        frag_ab af0, af1;
        PACK_AF(af0, a0, a1);
        PACK_AF(af1, a2, a3);

        const frag_ab* bp = wb + (size_t)c * 1024;
#pragma unroll
        for (int nt = 0; nt < 8; ++nt) {
            frag_ab bf0 = bp[(nt * 2 + 0) * 64];
            acc[nt] = __builtin_amdgcn_mfma_f32_16x16x32_bf16(af0, bf0, acc[nt], 0, 0, 0);
            frag_ab bf1 = bp[(nt * 2 + 1) * 64];
            acc[nt] = __builtin_amdgcn_mfma_f32_16x16x32_bf16(af1, bf1, acc[nt], 0, 0, 0);
        }
        if (c < 15) { a0 = n0; a1 = n1; a2 = n2; a3 = n3; }
    }

    // C/D: col = lane&15 (=h within tile), row = kg*4 + r
#pragma unroll
    for (int nt = 0; nt < 8; ++nt)
#pragma unroll
        for (int r = 0; r < 4; ++r) {
            long row = rowbase + kg * 4 + r;
            vm[row * 128 + nt * 16 + m] = acc[nt][r];
        }
}

// combine: out[b,k] = bias[k] + sum_h (v[b,h]/l[b,h]) * exp2(log2e*mask[b,h]*cov[h,k])
// 2048 blocks x 512 threads, obuf[2] (33.8 KB LDS) + cap 85 VGPR -> 3 blocks/CU
// (24 waves/CU) for latency hiding. 8 b's per block, 2 per barrier round.
// Thread (i=t>>4 in 0..31, j=t&15) owns h in [4i,4i+4), k in [8j,8j+8).
// covreg[4][8] = 32 VGPRs. lsum via DPP row_ror chain (VALU pipe).
__global__ __launch_bounds__(512, 6) void combine_kernel(const float* __restrict__ vm,
                                                         const float* __restrict__ cov,
                                                         const float* __restrict__ bias,
                                                         float* __restrict__ out) {
    __shared__ float obuf[2][32][132];   // 33.8 KB

    const int t = threadIdx.x;
    const int i = t >> 4;   // h-group 0..31
    const int j = t & 15;   // k-group 0..15
    const float bias_own = bias[t & 127];

    float covreg[4][8];
#pragma unroll
    for (int hh = 0; hh < 4; ++hh) {
        const float* cr = cov + (long)(i * 4 + hh) * 128 + j * 8;
        float4 c0 = *(const float4*)cr;
        float4 c1 = *(const float4*)(cr + 4);
        covreg[hh][0] = LOG2E * c0.x; covreg[hh][1] = LOG2E * c0.y;
        covreg[hh][2] = LOG2E * c0.z; covreg[hh][3] = LOG2E * c0.w;
        covreg[hh][4] = LOG2E * c1.x; covreg[hh][5] = LOG2E * c1.y;
        covreg[hh][6] = LOG2E * c1.z; covreg[hh][7] = LOG2E * c1.w;
    }

    const long b0 = (long)blockIdx.x * 8;
    for (int rr = 0; rr < 4; ++rr) {
#pragma unroll
        for (int sb = 0; sb < 2; ++sb) {
            const long b = b0 + rr * 2 + sb;
            // broadcast: all 16 lanes of a j-row read the same 16 B (cache-hot vm)
            float4 v4 = *(const float4*)(vm + (2 * b) * 128 + i * 4);
            float4 m4 = *(const float4*)(vm + (2 * b + 1) * 128 + i * 4);
            float vh[4] = {v4.x, v4.y, v4.z, v4.w};
            float mh[4] = {m4.x, m4.y, m4.z, m4.w};
            float op[8] = {0.f, 0.f, 0.f, 0.f, 0.f, 0.f, 0.f, 0.f};
#pragma unroll
            for (int hh = 0; hh < 4; ++hh) {
                float mv = mh[hh];
                float p[8];
#pragma unroll
                for (int kk = 0; kk < 8; ++kk)
                    p[kk] = __builtin_amdgcn_exp2f(mv * covreg[hh][kk]);
                float s0 = p[0] + p[1], s1 = p[2] + p[3];
                float s2 = p[4] + p[5], s3 = p[6] + p[7];
                float lsum = (s0 + s1) + (s2 + s3);
                lsum = dpp_ror_add<0x121>(lsum);   // row_ror:1
                lsum = dpp_ror_add<0x122>(lsum);   // row_ror:2
                lsum = dpp_ror_add<0x124>(lsum);   // row_ror:4
                lsum = dpp_ror_add<0x128>(lsum);   // row_ror:8
                float w = vh[hh] * __builtin_amdgcn_rcpf(lsum);
#pragma unroll
                for (int kk = 0; kk < 8; ++kk) op[kk] = fmaf(w, p[kk], op[kk]);
            }
            *(float4*)&obuf[sb][i][j * 8]     = make_float4(op[0], op[1], op[2], op[3]);
            *(float4*)&obuf[sb][i][j * 8 + 4] = make_float4(op[4], op[5], op[6], op[7]);
        }
        __syncthreads();
        // threads 0..255 reduce 2 sub-b x 128 k: sb = t>>7, k = t&127
        if (t < 256) {
            const int k  = t & 127;
            const int sb = t >> 7;
            float o = bias_own;
#pragma unroll
            for (int ii = 0; ii < 32; ++ii) o += obuf[sb][ii][k];
            out[(b0 + rr * 2 + sb) * 128 + k] = o;
        }
        __syncthreads();
    }
}

extern "C" void kernel_launch(void* const* d_in, const int* in_sizes, int n_in,
                              void* d_out, int out_size, void* d_ws, size_t ws_size,
                              hipStream_t stream) {
    const float* x    = (const float*)d_in[0];
    const float* W    = (const float*)d_in[1];
    const float* cov  = (const float*)d_in[2];
    const float* bias = (const float*)d_in[3];
    float* out = (float*)d_out;

    const int B = in_sizes[0] / (2 * 1024);   // 16384

    short* wbf = (short*)d_ws;                          // [128*1024] bf16, frag order
    float* vm  = (float*)(wbf + 128 * 1024);            // [2B][128] fp32

    prep_kernel<<<64, 256, 0, stream>>>(W, wbf);
    proj_kernel<<<(2 * B) / 64, 256, 0, stream>>>(x, wbf, vm);
    combine_kernel<<<B / 8, 512, 0, stream>>>(vm, cov, bias, out);
}

// Round 8
// 266.964 us; speedup vs baseline: 1.1625x; 1.1625x over previous
//
#include <hip/hip_runtime.h>

#define LOG2E 1.4426950408889634f

typedef __attribute__((ext_vector_type(8))) short frag_ab;   // 8 bf16 (4 VGPRs)
typedef __attribute__((ext_vector_type(4))) float frag_cd;   // 4 fp32 acc

// fp32 -> bf16 bits, round-to-nearest-even (inputs finite)
__device__ inline short f2bf(float f) {
    union { float f; unsigned u; } v; v.f = f;
    unsigned r = v.u + 0x7fffu + ((v.u >> 16) & 1u);
    return (short)(r >> 16);
}

// x += row_ror<N>(x) on the VALU pipe (DPP), within each 16-lane row.
template<int CTRL>
__device__ inline float dpp_ror_add(float x) {
    int t = __builtin_amdgcn_update_dpp(0, __builtin_bit_cast(int, x), CTRL, 0xf, 0xf, false);
    return x + __builtin_bit_cast(float, t);
}

// pack 4+4 floats into one bf16 fragment
#define PACK_AF(af, p0, p1)                                                   \
    af[0] = f2bf(p0.x); af[1] = f2bf(p0.y); af[2] = f2bf(p0.z); af[3] = f2bf(p0.w); \
    af[4] = f2bf(p1.x); af[5] = f2bf(p1.y); af[6] = f2bf(p1.z); af[7] = f2bf(p1.w);

// Convert W[128][1024] fp32 -> wbf bf16 in MFMA *fragment order*:
//   element (h,k): chunk c=k>>6, kstep s=(k>>5)&1, kg=(k>>3)&3, j=k&7,
//   ntile nt=h>>4, m=h&15, lane=kg*16+m
//   wbf[ (((c*8+nt)*2+s)*64 + lane)*8 + j ]
__global__ __launch_bounds__(256) void prep_kernel(const float* __restrict__ W,
                                                   short* __restrict__ wbf) {
    int g = blockIdx.x * 256 + threadIdx.x;   // 0..16383
    int h = g >> 7;
    int k0 = (g & 127) << 3;
    const float* src = W + h * 1024 + k0;
    float4 w0 = *(const float4*)src;
    float4 w1 = *(const float4*)(src + 4);
    frag_ab af;
    PACK_AF(af, w0, w1);
    int c = k0 >> 6, s = (k0 >> 5) & 1, kg = (k0 >> 3) & 3;
    int nt = h >> 4, m = h & 15, lane = kg * 16 + m;
    int dst = (((c * 8 + nt) * 2 + s) * 64 + lane) * 8;
    *(frag_ab*)(wbf + dst) = af;
}

// proj: vm[row][h] = sum_k x[row][k]*W[h][k].
// 32 rows/block, grid 1024 (4 blocks/CU, 16 waves/CU) -- 2x the TLP of the
// 64-row version whose grid capped the device at 2 waves/SIMD.
// Barrier-free, no LDS: wave (rg=w&1, nh=w>>1) owns rows [rg*16,rg*16+16) x
// n-tiles [nh*4, nh*4+4). B fragments read straight from wbf (256 KB,
// L1/L2-resident). A (x) prefetched 1 chunk ahead in registers.
__global__ __launch_bounds__(256, 4) void proj_kernel(const float* __restrict__ x,
                                                      const short* __restrict__ wbf,
                                                      float* __restrict__ vm) {
    const int tid = threadIdx.x;
    const int lane = tid & 63, wave = tid >> 6;
    const int rg = wave & 1, nh = wave >> 1;
    const int m = lane & 15, kg = lane >> 4;
    const long rowbase = (long)blockIdx.x * 32 + rg * 16;
    const float* xrow = x + (rowbase + m) * 1024 + kg * 8;
    // frag pointer for this lane; frag index ((c*8+nt)*2+s)*64 + lane
    const frag_ab* wb = (const frag_ab*)wbf + lane;

    frag_cd acc[4];
#pragma unroll
    for (int ntl = 0; ntl < 4; ++ntl) acc[ntl] = (frag_cd){0.f, 0.f, 0.f, 0.f};

    // prefetch A chunk 0
    float4 a0 = *(const float4*)(xrow);
    float4 a1 = *(const float4*)(xrow + 4);
    float4 a2 = *(const float4*)(xrow + 32);
    float4 a3 = *(const float4*)(xrow + 36);

    for (int c = 0; c < 16; ++c) {
        float4 n0, n1, n2, n3;
        if (c < 15) {
            const float* xn = xrow + (c + 1) * 64;
            n0 = *(const float4*)(xn);
            n1 = *(const float4*)(xn + 4);
            n2 = *(const float4*)(xn + 32);
            n3 = *(const float4*)(xn + 36);
        }
        frag_ab af0, af1;
        PACK_AF(af0, a0, a1);
        PACK_AF(af1, a2, a3);

        // this wave's 8 B-frags of chunk c: nt = nh*4+ntl, s in {0,1}
        const frag_ab* bp = wb + ((size_t)c * 8 + nh * 4) * 2 * 64;
#pragma unroll
        for (int ntl = 0; ntl < 4; ++ntl) {
            frag_ab bf0 = bp[(ntl * 2 + 0) * 64];
            acc[ntl] = __builtin_amdgcn_mfma_f32_16x16x32_bf16(af0, bf0, acc[ntl], 0, 0, 0);
            frag_ab bf1 = bp[(ntl * 2 + 1) * 64];
            acc[ntl] = __builtin_amdgcn_mfma_f32_16x16x32_bf16(af1, bf1, acc[ntl], 0, 0, 0);
        }
        if (c < 15) { a0 = n0; a1 = n1; a2 = n2; a3 = n3; }
    }

    // C/D: col = lane&15 (=h within tile), row = kg*4 + r
#pragma unroll
    for (int ntl = 0; ntl < 4; ++ntl)
#pragma unroll
        for (int r = 0; r < 4; ++r) {
            long row = rowbase + kg * 4 + r;
            vm[row * 128 + (nh * 4 + ntl) * 16 + m] = acc[ntl][r];
        }
}

// combine: out[b,k] = bias[k] + sum_h (v[b,h]/l[b,h]) * exp2(log2e*mask[b,h]*cov[h,k])
// 2048 blocks x 512 threads (launch_bounds (512,4): VGPR cap 128 -- the (512,6)
// cap of ~84 made the allocator spill to scratch: VGPR=40, +350 MB HBM traffic,
// 98 us. Reverted to the proven r5 config.)
// Thread (i=t>>4 in 0..31, j=t&15) owns h in [4i,4i+4), k in [8j,8j+8).
// covreg[4][8] = 32 VGPRs. lsum via DPP row_ror chain (VALU pipe).
// 4 b's per barrier round via obuf[4].
__global__ __launch_bounds__(512, 4) void combine_kernel(const float* __restrict__ vm,
                                                         const float* __restrict__ cov,
                                                         const float* __restrict__ bias,
                                                         float* __restrict__ out) {
    __shared__ float obuf[4][32][132];   // 67.6 KB

    const int t = threadIdx.x;
    const int i = t >> 4;   // h-group 0..31
    const int j = t & 15;   // k-group 0..15
    const float bias_own = bias[t & 127];

    float covreg[4][8];
#pragma unroll
    for (int hh = 0; hh < 4; ++hh) {
        const float* cr = cov + (long)(i * 4 + hh) * 128 + j * 8;
        float4 c0 = *(const float4*)cr;
        float4 c1 = *(const float4*)(cr + 4);
        covreg[hh][0] = LOG2E * c0.x; covreg[hh][1] = LOG2E * c0.y;
        covreg[hh][2] = LOG2E * c0.z; covreg[hh][3] = LOG2E * c0.w;
        covreg[hh][4] = LOG2E * c1.x; covreg[hh][5] = LOG2E * c1.y;
        covreg[hh][6] = LOG2E * c1.z; covreg[hh][7] = LOG2E * c1.w;
    }

    const long b0 = (long)blockIdx.x * 8;
    for (int rr = 0; rr < 2; ++rr) {
#pragma unroll
        for (int sb = 0; sb < 4; ++sb) {
            const long b = b0 + rr * 4 + sb;
            // broadcast: all 16 lanes of a j-row read the same 16 B (cache-hot vm)
            float4 v4 = *(const float4*)(vm + (2 * b) * 128 + i * 4);
            float4 m4 = *(const float4*)(vm + (2 * b + 1) * 128 + i * 4);
            float vh[4] = {v4.x, v4.y, v4.z, v4.w};
            float mh[4] = {m4.x, m4.y, m4.z, m4.w};
            float op[8] = {0.f, 0.f, 0.f, 0.f, 0.f, 0.f, 0.f, 0.f};
#pragma unroll
            for (int hh = 0; hh < 4; ++hh) {
                float mv = mh[hh];
                float p[8];
#pragma unroll
                for (int kk = 0; kk < 8; ++kk)
                    p[kk] = __builtin_amdgcn_exp2f(mv * covreg[hh][kk]);
                float s0 = p[0] + p[1], s1 = p[2] + p[3];
                float s2 = p[4] + p[5], s3 = p[6] + p[7];
                float lsum = (s0 + s1) + (s2 + s3);
                lsum = dpp_ror_add<0x121>(lsum);   // row_ror:1
                lsum = dpp_ror_add<0x122>(lsum);   // row_ror:2
                lsum = dpp_ror_add<0x124>(lsum);   // row_ror:4
                lsum = dpp_ror_add<0x128>(lsum);   // row_ror:8
                float w = vh[hh] * __builtin_amdgcn_rcpf(lsum);
#pragma unroll
                for (int kk = 0; kk < 8; ++kk) op[kk] = fmaf(w, p[kk], op[kk]);
            }
            *(float4*)&obuf[sb][i][j * 8]     = make_float4(op[0], op[1], op[2], op[3]);
            *(float4*)&obuf[sb][i][j * 8 + 4] = make_float4(op[4], op[5], op[6], op[7]);
        }
        __syncthreads();
        // 512 threads reduce 4 sub-b x 128 k: thread t -> sb = t>>7, k = t&127
        {
            const int k  = t & 127;
            const int sb = t >> 7;
            float o = bias_own;
#pragma unroll
            for (int ii = 0; ii < 32; ++ii) o += obuf[sb][ii][k];
            out[(b0 + rr * 4 + sb) * 128 + k] = o;
        }
        __syncthreads();
    }
}

extern "C" void kernel_launch(void* const* d_in, const int* in_sizes, int n_in,
                              void* d_out, int out_size, void* d_ws, size_t ws_size,
                              hipStream_t stream) {
    const float* x    = (const float*)d_in[0];
    const float* W    = (const float*)d_in[1];
    const float* cov  = (const float*)d_in[2];
    const float* bias = (const float*)d_in[3];
    float* out = (float*)d_out;

    const int B = in_sizes[0] / (2 * 1024);   // 16384

    short* wbf = (short*)d_ws;                          // [128*1024] bf16, frag order
    float* vm  = (float*)(wbf + 128 * 1024);            // [2B][128] fp32

    prep_kernel<<<64, 256, 0, stream>>>(W, wbf);
    proj_kernel<<<(2 * B) / 32, 256, 0, stream>>>(x, wbf, vm);
    combine_kernel<<<B / 8, 512, 0, stream>>>(vm, cov, bias, out);
}